// Round 1
// baseline (4279.179 us; speedup 1.0000x reference)
//
#include <hip/hip_runtime.h>
#include <cstddef>

static constexpr int HID = 1024;   // hidden
static constexpr int NB  = 4;      // batch
static constexpr int TT  = 2048;   // sequence length (Ti == Tt)
static constexpr int UD  = 4096;   // conv units

static constexpr int BM = 128, BN = 128, BK = 16;

// ---------------- gather + scale: out[row,:] = emb[idx[row],:] * scale ----
__global__ __launch_bounds__(256) void gather_rows_k(
    const int* __restrict__ idx, const float* __restrict__ emb,
    float* __restrict__ out, float scale)
{
  const int row = blockIdx.x;
  const int r = idx[row];
  const float4* src = (const float4*)(emb + (size_t)r * HID);
  float4* dst = (float4*)(out + (size_t)row * HID);
  float4 v = src[threadIdx.x];
  v.x *= scale; v.y *= scale; v.z *= scale; v.w *= scale;
  dst[threadIdx.x] = v;
}

// ---------------- in-place row softmax over TT(=2048) columns ------------
__global__ __launch_bounds__(256) void softmax_rows_k(float* __restrict__ L)
{
  float* row = L + (size_t)blockIdx.x * TT;
  const int tid = threadIdx.x;
  float4 v0 = ((const float4*)row)[tid * 2];
  float4 v1 = ((const float4*)row)[tid * 2 + 1];
  float mx = fmaxf(fmaxf(fmaxf(v0.x, v0.y), fmaxf(v0.z, v0.w)),
                   fmaxf(fmaxf(v1.x, v1.y), fmaxf(v1.z, v1.w)));
#pragma unroll
  for (int off = 32; off > 0; off >>= 1)
    mx = fmaxf(mx, __shfl_xor(mx, off, 64));
  __shared__ float sred[8];
  const int wid = tid >> 6;
  if ((tid & 63) == 0) sred[wid] = mx;
  __syncthreads();
  mx = fmaxf(fmaxf(sred[0], sred[1]), fmaxf(sred[2], sred[3]));
  v0.x = __expf(v0.x - mx); v0.y = __expf(v0.y - mx);
  v0.z = __expf(v0.z - mx); v0.w = __expf(v0.w - mx);
  v1.x = __expf(v1.x - mx); v1.y = __expf(v1.y - mx);
  v1.z = __expf(v1.z - mx); v1.w = __expf(v1.w - mx);
  float s = v0.x + v0.y + v0.z + v0.w + v1.x + v1.y + v1.z + v1.w;
#pragma unroll
  for (int off = 32; off > 0; off >>= 1)
    s += __shfl_xor(s, off, 64);
  if ((tid & 63) == 0) sred[4 + wid] = s;
  __syncthreads();
  s = sred[4] + sred[5] + sred[6] + sred[7];
  const float inv = 1.0f / s;
  v0.x *= inv; v0.y *= inv; v0.z *= inv; v0.w *= inv;
  v1.x *= inv; v1.y *= inv; v1.z *= inv; v1.w *= inv;
  ((float4*)row)[tid * 2]     = v0;
  ((float4*)row)[tid * 2 + 1] = v1;
}

// ---------------- generic 128x128x16 fp32 GEMM ---------------------------
// AMODE 0: A[m,k] row-major K-contig (NT-style A)
// AMODE 1: conv A: A[m,kk] = attn[m + (kk>>10) - 1, kk&1023], 0-padded rows
// BMODE 0: B[n,k] row-major K-contig (NT, transpose-store to LDS)
// BMODE 1: B[k,n] row-major N-contig (NN, direct store)
// EPI 0: none; 1: +bias[n]; 2: relu(+bias[n])
template<int AMODE, int BMODE, int EPI>
__global__ __launch_bounds__(256) void gemm_tile_k(
    const float* __restrict__ A, long long sA, int lda,
    const float* __restrict__ Bm, long long sB, int ldb,
    float* __restrict__ C, long long sC, int ldc,
    int K, int Abound, const float* __restrict__ bias)
{
  __shared__ float As[BK][BM + 4];
  __shared__ float Bs[BK][BN + 4];
  const int tid = threadIdx.x;
  A  += (size_t)blockIdx.z * sA;
  Bm += (size_t)blockIdx.z * sB;
  C  += (size_t)blockIdx.z * sC;
  const int bm = blockIdx.y * BM;
  const int bn = blockIdx.x * BN;
  const int tx = tid & 15, ty = tid >> 4;

  float acc[8][8];
#pragma unroll
  for (int i = 0; i < 8; ++i)
#pragma unroll
    for (int j = 0; j < 8; ++j) acc[i][j] = 0.f;

  const int arow = tid >> 1;        // 0..127
  const int akh  = (tid & 1) * 8;   // 0 or 8
  const int bn4  = (tid & 31) * 4;  // 0..124
  const int bk   = tid >> 5;        // 0..7

  for (int k0 = 0; k0 < K; k0 += BK) {
    float4 a0, a1;
    if constexpr (AMODE == 0) {
      const float* pa = A + (size_t)(bm + arow) * lda + (k0 + akh);
      a0 = *(const float4*)pa;
      a1 = *(const float4*)(pa + 4);
    } else {
      const int seg  = k0 >> 10;
      const int c0   = (k0 & 1023) + akh;
      const int srow = bm + arow + seg - 1;
      if (srow >= 0 && srow < Abound) {
        const float* pa = A + (size_t)srow * lda + c0;
        a0 = *(const float4*)pa;
        a1 = *(const float4*)(pa + 4);
      } else {
        a0 = make_float4(0.f, 0.f, 0.f, 0.f);
        a1 = make_float4(0.f, 0.f, 0.f, 0.f);
      }
    }
    {
      const float* f = (const float*)&a0;
#pragma unroll
      for (int i = 0; i < 4; ++i) As[akh + i][arow] = f[i];
      f = (const float*)&a1;
#pragma unroll
      for (int i = 0; i < 4; ++i) As[akh + 4 + i][arow] = f[i];
    }
    if constexpr (BMODE == 0) {
      const float* pb = Bm + (size_t)(bn + arow) * ldb + (k0 + akh);
      float4 b0 = *(const float4*)pb;
      float4 b1 = *(const float4*)(pb + 4);
      const float* f = (const float*)&b0;
#pragma unroll
      for (int i = 0; i < 4; ++i) Bs[akh + i][arow] = f[i];
      f = (const float*)&b1;
#pragma unroll
      for (int i = 0; i < 4; ++i) Bs[akh + 4 + i][arow] = f[i];
    } else {
      const float* pb = Bm + (size_t)(k0 + bk) * ldb + (bn + bn4);
      float4 b0 = *(const float4*)pb;
      float4 b1 = *(const float4*)(pb + (size_t)8 * ldb);
      *(float4*)&Bs[bk][bn4]     = b0;
      *(float4*)&Bs[bk + 8][bn4] = b1;
    }
    __syncthreads();

#pragma unroll
    for (int kk = 0; kk < BK; ++kk) {
      float4 A0 = *(const float4*)&As[kk][ty * 4];
      float4 A1 = *(const float4*)&As[kk][ty * 4 + 64];
      float4 B0 = *(const float4*)&Bs[kk][tx * 4];
      float4 B1 = *(const float4*)&Bs[kk][tx * 4 + 64];
      float av[8] = {A0.x, A0.y, A0.z, A0.w, A1.x, A1.y, A1.z, A1.w};
      float bv[8] = {B0.x, B0.y, B0.z, B0.w, B1.x, B1.y, B1.z, B1.w};
#pragma unroll
      for (int i = 0; i < 8; ++i)
#pragma unroll
        for (int j = 0; j < 8; ++j)
          acc[i][j] = fmaf(av[i], bv[j], acc[i][j]);
    }
    __syncthreads();
  }

#pragma unroll
  for (int ih = 0; ih < 2; ++ih)
#pragma unroll
    for (int i = 0; i < 4; ++i) {
      const int r = bm + ih * 64 + ty * 4 + i;
#pragma unroll
      for (int jh = 0; jh < 2; ++jh) {
        const int c = bn + jh * 64 + tx * 4;
        float4 v;
        v.x = acc[ih * 4 + i][jh * 4 + 0];
        v.y = acc[ih * 4 + i][jh * 4 + 1];
        v.z = acc[ih * 4 + i][jh * 4 + 2];
        v.w = acc[ih * 4 + i][jh * 4 + 3];
        if constexpr (EPI >= 1) {
          v.x += bias[c + 0]; v.y += bias[c + 1];
          v.z += bias[c + 2]; v.w += bias[c + 3];
        }
        if constexpr (EPI == 2) {
          v.x = fmaxf(v.x, 0.f); v.y = fmaxf(v.y, 0.f);
          v.z = fmaxf(v.z, 0.f); v.w = fmaxf(v.w, 0.f);
        }
        *(float4*)&C[(size_t)r * ldc + c] = v;
      }
    }
}

extern "C" void kernel_launch(void* const* d_in, const int* in_sizes, int n_in,
                              void* d_out, int out_size, void* d_ws, size_t ws_size,
                              hipStream_t stream)
{
  const int*   inputs     = (const int*)d_in[0];
  const int*   targets    = (const int*)d_in[1];
  const float* input_emb  = (const float*)d_in[2];
  const float* target_emb = (const float*)d_in[3];
  const float* conv_w     = (const float*)d_in[4];
  const float* conv_b     = (const float*)d_in[5];
  const float* dense_w    = (const float*)d_in[6];
  const float* dense_b    = (const float*)d_in[7];
  float* out = (float*)d_out;
  float* ws  = (float*)d_ws;

  const long long S_ET = (long long)TT * HID;  // 2,097,152 floats (one batch of te/ie/attn/out)
  const long long S_L  = (long long)TT * TT;   // 4,194,304 floats (one batch of logits)
  const long long S_H  = (long long)TT * UD;   // 8,388,608 floats (one batch of h)

  const size_t need_full = (size_t)(4 * S_ET + 4 * S_H) * sizeof(float); // 167.8 MB

  if (ws_size >= need_full) {
    // layout: [attn 4*S_ET][ie 4*S_ET][te 4*S_ET][logits 4*S_L]
    // hbuf (4*S_H) overlays ie/te/logits after attention completes.
    float* attn   = ws;
    float* ie     = ws + 4 * S_ET;
    float* te     = ws + 8 * S_ET;
    float* logits = ws + 12 * S_ET;
    float* hbuf   = ws + 4 * S_ET;

    gather_rows_k<<<NB * TT, 256, 0, stream>>>(inputs, input_emb, ie, 32.0f);
    gather_rows_k<<<NB * TT, 256, 0, stream>>>(targets, target_emb, te, 1.0f);
    // logits[t,s] = sum_h te_raw[t,h] * ie_scaled[s,h]  ( == 32 * te_raw.ie_raw )
    gemm_tile_k<0, 0, 0><<<dim3(TT / BN, TT / BM, NB), 256, 0, stream>>>(
        te, S_ET, HID, ie, S_ET, HID, logits, S_L, TT, HID, TT, nullptr);
    softmax_rows_k<<<NB * TT, 256, 0, stream>>>(logits);
    // attn[t,h] = sum_s W[t,s] * ie[s,h]
    gemm_tile_k<0, 1, 0><<<dim3(HID / BN, TT / BM, NB), 256, 0, stream>>>(
        logits, S_L, TT, ie, S_ET, HID, attn, S_ET, HID, TT, TT, nullptr);
    // h[t,u] = relu(conv_b[u] + sum_{k,c} attn[t+k-1,c] conv_w[k,c,u])
    gemm_tile_k<1, 1, 2><<<dim3(UD / BN, TT / BM, NB), 256, 0, stream>>>(
        attn, S_ET, HID, conv_w, 0, UD, hbuf, S_H, UD, 3 * HID, TT, conv_b);
    // out[t,h] = dense_b[h] + sum_u h[t,u] dense_w[u,h]
    gemm_tile_k<0, 1, 1><<<dim3(HID / BN, TT / BM, NB), 256, 0, stream>>>(
        hbuf, S_H, UD, dense_w, 0, HID, out, S_ET, HID, UD, TT, dense_b);
  } else {
    // low-footprint per-batch path (peak 41.9 MB):
    // [attn S_ET][ie S_ET][te S_ET][logits S_L]; hbuf (S_H) overlays ie/te/logits
    float* attn   = ws;
    float* ie     = ws + S_ET;
    float* te     = ws + 2 * S_ET;
    float* logits = ws + 3 * S_ET;
    float* hbuf   = ws + S_ET;
    for (int b = 0; b < NB; ++b) {
      gather_rows_k<<<TT, 256, 0, stream>>>(inputs + b * TT, input_emb, ie, 32.0f);
      gather_rows_k<<<TT, 256, 0, stream>>>(targets + b * TT, target_emb, te, 1.0f);
      gemm_tile_k<0, 0, 0><<<dim3(TT / BN, TT / BM, 1), 256, 0, stream>>>(
          te, 0, HID, ie, 0, HID, logits, 0, TT, HID, TT, nullptr);
      softmax_rows_k<<<TT, 256, 0, stream>>>(logits);
      gemm_tile_k<0, 1, 0><<<dim3(HID / BN, TT / BM, 1), 256, 0, stream>>>(
          logits, 0, TT, ie, 0, HID, attn, 0, HID, TT, TT, nullptr);
      gemm_tile_k<1, 1, 2><<<dim3(UD / BN, TT / BM, 1), 256, 0, stream>>>(
          attn, 0, HID, conv_w, 0, UD, hbuf, 0, UD, 3 * HID, TT, conv_b);
      gemm_tile_k<0, 1, 1><<<dim3(HID / BN, TT / BM, 1), 256, 0, stream>>>(
          hbuf, 0, UD, dense_w, 0, HID, out + (size_t)b * S_ET, 0, HID, UD, TT, dense_b);
    }
  }
}

// Round 2
// 1391.413 us; speedup vs baseline: 3.0754x; 3.0754x over previous
//
#include <hip/hip_runtime.h>
#include <cstddef>

static constexpr int HID = 1024;   // hidden
static constexpr int NB  = 4;      // batch
static constexpr int TT  = 2048;   // sequence (Ti == Tt)
static constexpr int UD  = 4096;   // conv units

typedef short bf8    __attribute__((ext_vector_type(8)));  // 8 bf16 (4 VGPRs)
typedef float f32x4  __attribute__((ext_vector_type(4)));  // MFMA C/D frag

__device__ __forceinline__ unsigned short f2bf(float x) {
  unsigned int u = __float_as_uint(x);
  u += 0x7fffu + ((u >> 16) & 1u);          // round-to-nearest-even
  return (unsigned short)(u >> 16);
}
__device__ __forceinline__ float bf2f(unsigned short h) {
  return __uint_as_float(((unsigned int)h) << 16);
}
__device__ __forceinline__ unsigned short cvt_bf(float x) { return f2bf(x); }
__device__ __forceinline__ unsigned short cvt_bf(unsigned short x) { return x; }

// ---- gather row + scale, split into bf16 hi/lo:  hi+lo ~= scale*emb[idx] ----
__global__ __launch_bounds__(256) void gather_split_k(
    const int* __restrict__ idx, const float* __restrict__ emb,
    unsigned short* __restrict__ hi, unsigned short* __restrict__ lo, float scale)
{
  const int row = blockIdx.x;
  const int r = idx[row];
  const int c = threadIdx.x * 4;
  float4 v = *(const float4*)(emb + (size_t)r * HID + c);
  v.x *= scale; v.y *= scale; v.z *= scale; v.w *= scale;
  ushort4 h, l;
  h.x = f2bf(v.x); h.y = f2bf(v.y); h.z = f2bf(v.z); h.w = f2bf(v.w);
  l.x = f2bf(v.x - bf2f(h.x)); l.y = f2bf(v.y - bf2f(h.y));
  l.z = f2bf(v.z - bf2f(h.z)); l.w = f2bf(v.w - bf2f(h.w));
  *(ushort4*)(hi + (size_t)row * HID + c) = h;
  *(ushort4*)(lo + (size_t)row * HID + c) = l;
}

// ---- generic transpose to bf16: out[c][r] = bf16(in[r][c]) ----------------
template<typename TIN>
__global__ __launch_bounds__(256) void transpose_bf_k(
    const TIN* __restrict__ in, unsigned short* __restrict__ out,
    int R, int C, long long sIn, long long sOut)
{
  __shared__ unsigned short tile[32][33];
  in  += (size_t)blockIdx.z * sIn;
  out += (size_t)blockIdx.z * sOut;
  const int r0 = blockIdx.y * 32, c0 = blockIdx.x * 32;
  const int tc = threadIdx.x & 31, tr8 = threadIdx.x >> 5;
#pragma unroll
  for (int p = 0; p < 4; ++p) {
    const int r = tr8 + p * 8;
    tile[r][tc] = cvt_bf(in[(size_t)(r0 + r) * C + c0 + tc]);
  }
  __syncthreads();
#pragma unroll
  for (int p = 0; p < 4; ++p) {
    const int c = tr8 + p * 8;
    out[(size_t)(c0 + c) * R + r0 + tc] = tile[tc][c];
  }
}

// ---- row softmax over TT cols: fp32 in -> bf16 out ------------------------
__global__ __launch_bounds__(256) void softmax_bf_k(
    const float* __restrict__ L, unsigned short* __restrict__ W)
{
  const float* row = L + (size_t)blockIdx.x * TT;
  unsigned short* wout = W + (size_t)blockIdx.x * TT;
  const int tid = threadIdx.x;
  float4 v0 = ((const float4*)row)[tid * 2];
  float4 v1 = ((const float4*)row)[tid * 2 + 1];
  float mx = fmaxf(fmaxf(fmaxf(v0.x, v0.y), fmaxf(v0.z, v0.w)),
                   fmaxf(fmaxf(v1.x, v1.y), fmaxf(v1.z, v1.w)));
#pragma unroll
  for (int off = 32; off > 0; off >>= 1)
    mx = fmaxf(mx, __shfl_xor(mx, off, 64));
  __shared__ float sred[8];
  const int wid = tid >> 6;
  if ((tid & 63) == 0) sred[wid] = mx;
  __syncthreads();
  mx = fmaxf(fmaxf(sred[0], sred[1]), fmaxf(sred[2], sred[3]));
  v0.x = __expf(v0.x - mx); v0.y = __expf(v0.y - mx);
  v0.z = __expf(v0.z - mx); v0.w = __expf(v0.w - mx);
  v1.x = __expf(v1.x - mx); v1.y = __expf(v1.y - mx);
  v1.z = __expf(v1.z - mx); v1.w = __expf(v1.w - mx);
  float s = v0.x + v0.y + v0.z + v0.w + v1.x + v1.y + v1.z + v1.w;
#pragma unroll
  for (int off = 32; off > 0; off >>= 1)
    s += __shfl_xor(s, off, 64);
  if ((tid & 63) == 0) sred[4 + wid] = s;
  __syncthreads();
  s = sred[4] + sred[5] + sred[6] + sred[7];
  const float inv = 1.0f / s;
  ushort4 o0, o1;
  o0.x = f2bf(v0.x * inv); o0.y = f2bf(v0.y * inv);
  o0.z = f2bf(v0.z * inv); o0.w = f2bf(v0.w * inv);
  o1.x = f2bf(v1.x * inv); o1.y = f2bf(v1.y * inv);
  o1.z = f2bf(v1.z * inv); o1.w = f2bf(v1.w * inv);
  *(ushort4*)(wout + tid * 8)     = o0;
  *(ushort4*)(wout + tid * 8 + 4) = o1;
}

// ---- bf16 MFMA GEMM: C[M][N] = A[M][K] . B[N][K]^T ------------------------
// 128x128 tile, BK=32, 256 thr = 4 waves, each wave 64x64 as 4x4 mfma 16x16x32.
// LDS layout [kblock][row][8] so fragment reads are contiguous ds_read_b128.
// BETA:  accumulate into existing fp32 C.
// OUTBF: write bf16 C (else fp32).
// EPI:   0 none, 1 +bias[n], 2 relu(+bias[n]).
// CONVA: A addressed as shifted conv im2col of attn[Abound][lda] (zero-pad rows).
template<int BETA, int OUTBF, int EPI, int CONVA>
__global__ __launch_bounds__(256) void gemm_bf16_k(
    const unsigned short* __restrict__ A, long long sA, int lda,
    const unsigned short* __restrict__ B, long long sB, int ldb,
    void* __restrict__ Cv, long long sC, int ldc,
    int K, int Abound, const float* __restrict__ bias)
{
  __shared__ unsigned short As[4 * 128 * 8];
  __shared__ unsigned short Bs[4 * 128 * 8];
  const int tid = threadIdx.x;
  A += (size_t)blockIdx.z * sA;
  B += (size_t)blockIdx.z * sB;
  const int bm = blockIdx.y * 128;
  const int bn = blockIdx.x * 128;
  const int wave = tid >> 6, lane = tid & 63;
  const int wr = wave >> 1, wc = wave & 1;
  const int q = lane >> 4, l16 = lane & 15;
  const int sr  = tid & 127;   // staging row
  const int skb = tid >> 7;    // staging k-block (0/1, +2 for 2nd chunk)

  f32x4 acc[4][4];
#pragma unroll
  for (int i = 0; i < 4; ++i)
#pragma unroll
    for (int j = 0; j < 4; ++j)
      acc[i][j] = (f32x4){0.f, 0.f, 0.f, 0.f};

  for (int k0 = 0; k0 < K; k0 += 32) {
#pragma unroll
    for (int h = 0; h < 2; ++h) {
      const int kb = skb + h * 2;
      const int kk = k0 + kb * 8;
      uint4 av;
      if constexpr (CONVA) {
        const int seg  = kk >> 10;
        const int srow = bm + sr + seg - 1;
        if (srow >= 0 && srow < Abound)
          av = *(const uint4*)(A + (size_t)srow * lda + (kk & 1023));
        else
          av = make_uint4(0u, 0u, 0u, 0u);
      } else {
        av = *(const uint4*)(A + (size_t)(bm + sr) * lda + kk);
      }
      *(uint4*)&As[(kb * 128 + sr) * 8] = av;
      uint4 bv = *(const uint4*)(B + (size_t)(bn + sr) * ldb + kk);
      *(uint4*)&Bs[(kb * 128 + sr) * 8] = bv;
    }
    __syncthreads();
    bf8 af[4], bfr[4];
#pragma unroll
    for (int i = 0; i < 4; ++i)
      af[i] = *(const bf8*)&As[(q * 128 + wr * 64 + i * 16 + l16) * 8];
#pragma unroll
    for (int j = 0; j < 4; ++j)
      bfr[j] = *(const bf8*)&Bs[(q * 128 + wc * 64 + j * 16 + l16) * 8];
#pragma unroll
    for (int i = 0; i < 4; ++i)
#pragma unroll
      for (int j = 0; j < 4; ++j)
        acc[i][j] = __builtin_amdgcn_mfma_f32_16x16x32_bf16(af[i], bfr[j], acc[i][j], 0, 0, 0);
    __syncthreads();
  }

  // epilogue: C/D frag mapping col=lane&15, row=quad*4+reg (m89/m91 verified)
  float* Cf          = (float*)Cv          + (size_t)blockIdx.z * sC;
  unsigned short* Cb = (unsigned short*)Cv + (size_t)blockIdx.z * sC;
#pragma unroll
  for (int j = 0; j < 4; ++j) {
    const int col = bn + wc * 64 + j * 16 + l16;
    float bv = 0.f;
    if constexpr (EPI >= 1) bv = bias[col];
#pragma unroll
    for (int i = 0; i < 4; ++i) {
      const int row0 = bm + wr * 64 + i * 16 + q * 4;
#pragma unroll
      for (int r = 0; r < 4; ++r) {
        float v = acc[i][j][r];
        if constexpr (BETA) v += Cf[(size_t)(row0 + r) * ldc + col];
        if constexpr (EPI >= 1) v += bv;
        if constexpr (EPI == 2) v = fmaxf(v, 0.f);
        if constexpr (OUTBF) Cb[(size_t)(row0 + r) * ldc + col] = f2bf(v);
        else                 Cf[(size_t)(row0 + r) * ldc + col] = v;
      }
    }
  }
}

extern "C" void kernel_launch(void* const* d_in, const int* in_sizes, int n_in,
                              void* d_out, int out_size, void* d_ws, size_t ws_size,
                              hipStream_t stream)
{
  const int*   inputs     = (const int*)d_in[0];
  const int*   targets    = (const int*)d_in[1];
  const float* input_emb  = (const float*)d_in[2];
  const float* target_emb = (const float*)d_in[3];
  const float* conv_w     = (const float*)d_in[4];
  const float* conv_b     = (const float*)d_in[5];
  const float* dense_w    = (const float*)d_in[6];
  const float* dense_b    = (const float*)d_in[7];
  float* out = (float*)d_out;

  const long long SE = (long long)TT * HID;        // 2,097,152 elem / batch
  const size_t SZ_BF_ET = (size_t)NB * SE * 2;     // 16,777,216 B (bf16, all batches)

  // workspace map (total exactly 167,772,160 B = round-1 proven capacity):
  // [0)        te_hi   -> later ieT
  // [1*SZ)     te_lo   -> later attn_bf16
  // [2*SZ)     ie_hi   -> later convw_bf (25.2MB spans into ie_lo)
  // [3*SZ)     ie_lo   -> later densew_bf tail
  // [4*SZ)     logits fp32 (67.1MB) -> later h_bf16
  // [4*SZ+67M) Wbf bf16 (33.6MB)
  char* base = (char*)d_ws;
  unsigned short* te_hi = (unsigned short*)(base);
  unsigned short* te_lo = (unsigned short*)(base + SZ_BF_ET);
  unsigned short* ie_hi = (unsigned short*)(base + 2 * SZ_BF_ET);
  unsigned short* ie_lo = (unsigned short*)(base + 3 * SZ_BF_ET);
  float*          logit = (float*)         (base + 4 * SZ_BF_ET);
  unsigned short* Wbf   = (unsigned short*)(base + 4 * SZ_BF_ET + (size_t)NB * TT * TT * 4);
  unsigned short* ieT    = (unsigned short*)(base);
  unsigned short* attnb  = (unsigned short*)(base + SZ_BF_ET);
  unsigned short* convwb = (unsigned short*)(base + 2 * SZ_BF_ET);
  unsigned short* densewb= (unsigned short*)(base + 2 * SZ_BF_ET + (size_t)UD * 3 * HID * 2);
  unsigned short* hb     = (unsigned short*)(base + 4 * SZ_BF_ET);

  // 1) gathers (te unscaled, ie scaled by sqrt(H)=32; logits = te_raw . ie_scaled)
  gather_split_k<<<NB * TT, 256, 0, stream>>>(targets, target_emb, te_hi, te_lo, 1.0f);
  gather_split_k<<<NB * TT, 256, 0, stream>>>(inputs,  input_emb,  ie_hi, ie_lo, 32.0f);

  // 2) logits = te_hi.ie_hi + te_hi.ie_lo + te_lo.ie_hi  (hi/lo split, fp32 C)
  dim3 gL(TT / 128, TT / 128, NB);
  gemm_bf16_k<0, 0, 0, 0><<<gL, 256, 0, stream>>>(
      te_hi, SE, HID, ie_hi, SE, HID, logit, (long long)TT * TT, TT, HID, 0, nullptr);
  gemm_bf16_k<1, 0, 0, 0><<<gL, 256, 0, stream>>>(
      te_hi, SE, HID, ie_lo, SE, HID, logit, (long long)TT * TT, TT, HID, 0, nullptr);
  gemm_bf16_k<1, 0, 0, 0><<<gL, 256, 0, stream>>>(
      te_lo, SE, HID, ie_hi, SE, HID, logit, (long long)TT * TT, TT, HID, 0, nullptr);

  // 3) ieT[h][s] = ie_hi[s][h]  (B operand for attn GEMM) — overwrites te_hi (dead)
  transpose_bf_k<unsigned short><<<dim3(HID / 32, TT / 32, NB), 256, 0, stream>>>(
      ie_hi, ieT, TT, HID, SE, SE);

  // 4) softmax rows -> bf16 weights
  softmax_bf_k<<<NB * TT, 256, 0, stream>>>(logit, Wbf);

  // 5) attn[t][h] = W[t][s] . ieT[h][s]  -> bf16 (overwrites te_lo, dead)
  gemm_bf16_k<0, 1, 0, 0><<<dim3(HID / 128, TT / 128, NB), 256, 0, stream>>>(
      Wbf, (long long)TT * TT, TT, ieT, SE, TT, attnb, SE, HID, TT, 0, nullptr);

  // 6) weight transposes (inputs only; te/ie regions dead now)
  transpose_bf_k<float><<<dim3(UD / 32, (3 * HID) / 32, 1), 256, 0, stream>>>(
      conv_w, convwb, 3 * HID, UD, 0, 0);
  transpose_bf_k<float><<<dim3(HID / 32, UD / 32, 1), 256, 0, stream>>>(
      dense_w, densewb, UD, HID, 0, 0);

  // 7) conv: h[t][u] = relu(b[u] + sum_{kk} Aconv[t][kk] convwb[u][kk]) -> bf16
  //    Aconv shifted-view of attnb, zero-padded per batch  (h overwrites logits, dead)
  gemm_bf16_k<0, 1, 2, 1><<<dim3(UD / 128, TT / 128, NB), 256, 0, stream>>>(
      attnb, SE, HID, convwb, 0, 3 * HID, hb, (long long)TT * UD, UD, 3 * HID, TT, conv_b);

  // 8) dense: out[t][h] = b[h] + h[t][u] . densewb[h][u]  (fp32 out)
  gemm_bf16_k<0, 0, 1, 0><<<dim3(HID / 128, TT / 128, NB), 256, 0, stream>>>(
      hb, (long long)TT * UD, UD, densewb, 0, UD, out, SE, HID, UD, 0, dense_b);
}

// Round 3
// 1131.991 us; speedup vs baseline: 3.7802x; 1.2292x over previous
//
#include <hip/hip_runtime.h>
#include <cstddef>

static constexpr int HID = 1024;   // hidden
static constexpr int NB  = 4;      // batch
static constexpr int TT  = 2048;   // sequence (Ti == Tt)
static constexpr int UD  = 4096;   // conv units
static constexpr int PR  = TT + 1; // padded row stride (guard row per batch)

typedef short bf8    __attribute__((ext_vector_type(8)));  // 8 bf16 (4 VGPRs)
typedef float f32x4  __attribute__((ext_vector_type(4)));  // MFMA C/D frag

__device__ __forceinline__ unsigned short f2bf(float x) {
  unsigned int u = __float_as_uint(x);
  u += 0x7fffu + ((u >> 16) & 1u);          // round-to-nearest-even
  return (unsigned short)(u >> 16);
}
__device__ __forceinline__ float bf2f(unsigned short h) {
  return __uint_as_float(((unsigned int)h) << 16);
}
__device__ __forceinline__ unsigned short cvt_bf(float x) { return f2bf(x); }
__device__ __forceinline__ unsigned short cvt_bf(unsigned short x) { return x; }

// async global->LDS, 16B per lane. LDS dest must be wave-uniform base + lane*16
// (m104/m108 caveat) — staging index (kb*128+sr)*8 satisfies this by construction.
__device__ __forceinline__ void g2l16(const unsigned short* g, unsigned short* l) {
  __builtin_amdgcn_global_load_lds(
      (const __attribute__((address_space(1))) unsigned int*)g,
      (__attribute__((address_space(3))) unsigned int*)l, 16, 0, 0);
}

// ---- gather row + scale, split into bf16 hi/lo:  hi+lo ~= scale*emb[idx] ----
__global__ __launch_bounds__(256) void gather_split_k(
    const int* __restrict__ idx, const float* __restrict__ emb,
    unsigned short* __restrict__ hi, unsigned short* __restrict__ lo, float scale)
{
  const int row = blockIdx.x;
  const int r = idx[row];
  const int c = threadIdx.x * 4;
  float4 v = *(const float4*)(emb + (size_t)r * HID + c);
  v.x *= scale; v.y *= scale; v.z *= scale; v.w *= scale;
  ushort4 h, l;
  h.x = f2bf(v.x); h.y = f2bf(v.y); h.z = f2bf(v.z); h.w = f2bf(v.w);
  l.x = f2bf(v.x - bf2f(h.x)); l.y = f2bf(v.y - bf2f(h.y));
  l.z = f2bf(v.z - bf2f(h.z)); l.w = f2bf(v.w - bf2f(h.w));
  *(ushort4*)(hi + (size_t)row * HID + c) = h;
  *(ushort4*)(lo + (size_t)row * HID + c) = l;
}

// ---- zero the 5 guard rows of the padded attn buffer ----------------------
__global__ __launch_bounds__(256) void zero_guard_k(unsigned short* __restrict__ p)
{
  unsigned short* row = p + (size_t)blockIdx.x * PR * HID;
  *(ushort4*)(row + threadIdx.x * 4) = (ushort4){0, 0, 0, 0};
}

// ---- generic transpose to bf16: out[c][r] = bf16(in[r][c]) ----------------
template<typename TIN>
__global__ __launch_bounds__(256) void transpose_bf_k(
    const TIN* __restrict__ in, unsigned short* __restrict__ out,
    int R, int C, long long sIn, long long sOut)
{
  __shared__ unsigned short tile[32][33];
  in  += (size_t)blockIdx.z * sIn;
  out += (size_t)blockIdx.z * sOut;
  const int r0 = blockIdx.y * 32, c0 = blockIdx.x * 32;
  const int tc = threadIdx.x & 31, tr8 = threadIdx.x >> 5;
#pragma unroll
  for (int p = 0; p < 4; ++p) {
    const int r = tr8 + p * 8;
    tile[r][tc] = cvt_bf(in[(size_t)(r0 + r) * C + c0 + tc]);
  }
  __syncthreads();
#pragma unroll
  for (int p = 0; p < 4; ++p) {
    const int c = tr8 + p * 8;
    out[(size_t)(c0 + c) * R + r0 + tc] = tile[tc][c];
  }
}

// ---- row softmax over TT cols: fp32 in -> bf16 out ------------------------
__global__ __launch_bounds__(256) void softmax_bf_k(
    const float* __restrict__ L, unsigned short* __restrict__ W)
{
  const float* row = L + (size_t)blockIdx.x * TT;
  unsigned short* wout = W + (size_t)blockIdx.x * TT;
  const int tid = threadIdx.x;
  float4 v0 = ((const float4*)row)[tid * 2];
  float4 v1 = ((const float4*)row)[tid * 2 + 1];
  float mx = fmaxf(fmaxf(fmaxf(v0.x, v0.y), fmaxf(v0.z, v0.w)),
                   fmaxf(fmaxf(v1.x, v1.y), fmaxf(v1.z, v1.w)));
#pragma unroll
  for (int off = 32; off > 0; off >>= 1)
    mx = fmaxf(mx, __shfl_xor(mx, off, 64));
  __shared__ float sred[8];
  const int wid = tid >> 6;
  if ((tid & 63) == 0) sred[wid] = mx;
  __syncthreads();
  mx = fmaxf(fmaxf(sred[0], sred[1]), fmaxf(sred[2], sred[3]));
  v0.x = __expf(v0.x - mx); v0.y = __expf(v0.y - mx);
  v0.z = __expf(v0.z - mx); v0.w = __expf(v0.w - mx);
  v1.x = __expf(v1.x - mx); v1.y = __expf(v1.y - mx);
  v1.z = __expf(v1.z - mx); v1.w = __expf(v1.w - mx);
  float s = v0.x + v0.y + v0.z + v0.w + v1.x + v1.y + v1.z + v1.w;
#pragma unroll
  for (int off = 32; off > 0; off >>= 1)
    s += __shfl_xor(s, off, 64);
  if ((tid & 63) == 0) sred[4 + wid] = s;
  __syncthreads();
  s = sred[4] + sred[5] + sred[6] + sred[7];
  const float inv = 1.0f / s;
  ushort4 o0, o1;
  o0.x = f2bf(v0.x * inv); o0.y = f2bf(v0.y * inv);
  o0.z = f2bf(v0.z * inv); o0.w = f2bf(v0.w * inv);
  o1.x = f2bf(v1.x * inv); o1.y = f2bf(v1.y * inv);
  o1.z = f2bf(v1.z * inv); o1.w = f2bf(v1.w * inv);
  *(ushort4*)(wout + tid * 8)     = o0;
  *(ushort4*)(wout + tid * 8 + 4) = o1;
}

// ---- bf16 MFMA GEMM: C[M][N] = A[M][K] . B[N][K]^T ------------------------
// 128x128 tile, BK=32, 4 waves, 64x64/wave as 4x4 mfma_f32_16x16x32_bf16.
// Staging via global_load_lds width=16 (m97). LDS [kblock][row][8].
// OUTBF: bf16 C (else fp32). EPI: 0 none, 1 +bias, 2 relu(+bias).
// CONVA: A is shifted conv view of padded attn (guard rows make it unconditional).
template<int OUTBF, int EPI, int CONVA>
__global__ __launch_bounds__(256) void gemm_bf16_k(
    const unsigned short* __restrict__ A, long long sA, int lda,
    const unsigned short* __restrict__ B, long long sB, int ldb,
    void* __restrict__ Cv, long long sC, int ldc,
    int K, const float* __restrict__ bias)
{
  __shared__ unsigned short As[4 * 128 * 8];
  __shared__ unsigned short Bs[4 * 128 * 8];
  const int tid = threadIdx.x;
  A += (size_t)blockIdx.z * sA;
  B += (size_t)blockIdx.z * sB;
  const int bm = blockIdx.y * 128;
  const int bn = blockIdx.x * 128;
  const int wave = tid >> 6, lane = tid & 63;
  const int wr = wave >> 1, wc = wave & 1;
  const int q = lane >> 4, l16 = lane & 15;
  const int sr  = tid & 127;   // staging row
  const int skb = tid >> 7;    // staging k-block

  f32x4 acc[4][4];
#pragma unroll
  for (int i = 0; i < 4; ++i)
#pragma unroll
    for (int j = 0; j < 4; ++j)
      acc[i][j] = (f32x4){0.f, 0.f, 0.f, 0.f};

  for (int k0 = 0; k0 < K; k0 += 32) {
#pragma unroll
    for (int h = 0; h < 2; ++h) {
      const int kb = skb + h * 2;
      const int kk = k0 + kb * 8;
      const unsigned short* pa;
      if constexpr (CONVA) {
        const int seg = kk >> 10;                       // wave-uniform
        pa = A + (ptrdiff_t)(bm + sr + seg - 1) * lda + (kk & 1023);
      } else {
        pa = A + (size_t)(bm + sr) * lda + kk;
      }
      g2l16(pa, &As[(kb * 128 + sr) * 8]);
      g2l16(B + (size_t)(bn + sr) * ldb + kk, &Bs[(kb * 128 + sr) * 8]);
    }
    __syncthreads();
    bf8 af[4], bfr[4];
#pragma unroll
    for (int i = 0; i < 4; ++i)
      af[i] = *(const bf8*)&As[(q * 128 + wr * 64 + i * 16 + l16) * 8];
#pragma unroll
    for (int j = 0; j < 4; ++j)
      bfr[j] = *(const bf8*)&Bs[(q * 128 + wc * 64 + j * 16 + l16) * 8];
#pragma unroll
    for (int i = 0; i < 4; ++i)
#pragma unroll
      for (int j = 0; j < 4; ++j)
        acc[i][j] = __builtin_amdgcn_mfma_f32_16x16x32_bf16(af[i], bfr[j], acc[i][j], 0, 0, 0);
    __syncthreads();
  }

  float* Cf          = (float*)Cv          + (size_t)blockIdx.z * sC;
  unsigned short* Cb = (unsigned short*)Cv + (size_t)blockIdx.z * sC;
#pragma unroll
  for (int j = 0; j < 4; ++j) {
    const int col = bn + wc * 64 + j * 16 + l16;
    float bv = 0.f;
    if constexpr (EPI >= 1) bv = bias[col];
#pragma unroll
    for (int i = 0; i < 4; ++i) {
      const int row0 = bm + wr * 64 + i * 16 + q * 4;
#pragma unroll
      for (int r = 0; r < 4; ++r) {
        float v = acc[i][j][r];
        if constexpr (EPI >= 1) v += bv;
        if constexpr (EPI == 2) v = fmaxf(v, 0.f);
        if constexpr (OUTBF) Cb[(size_t)(row0 + r) * ldc + col] = f2bf(v);
        else                 Cf[(size_t)(row0 + r) * ldc + col] = v;
      }
    }
  }
}

// ---- fused hi/lo logits GEMM: C = Ah.Bh^T + Ah.Bl^T + Al.Bh^T (fp32 C) ----
// Fixed shapes: lda=ldb=HID, M=N=TT, K=HID, ldc=TT.
__global__ __launch_bounds__(256) void gemm_logits_k(
    const unsigned short* __restrict__ Ah, const unsigned short* __restrict__ Al,
    const unsigned short* __restrict__ Bh, const unsigned short* __restrict__ Bl,
    float* __restrict__ C)
{
  __shared__ unsigned short AsH[4 * 128 * 8], AsL[4 * 128 * 8];
  __shared__ unsigned short BsH[4 * 128 * 8], BsL[4 * 128 * 8];
  const int tid = threadIdx.x;
  const long long SE = (long long)TT * HID;
  Ah += (size_t)blockIdx.z * SE; Al += (size_t)blockIdx.z * SE;
  Bh += (size_t)blockIdx.z * SE; Bl += (size_t)blockIdx.z * SE;
  C  += (size_t)blockIdx.z * TT * TT;
  const int bm = blockIdx.y * 128;
  const int bn = blockIdx.x * 128;
  const int wave = tid >> 6, lane = tid & 63;
  const int wr = wave >> 1, wc = wave & 1;
  const int q = lane >> 4, l16 = lane & 15;
  const int sr  = tid & 127;
  const int skb = tid >> 7;

  f32x4 acc[4][4];
#pragma unroll
  for (int i = 0; i < 4; ++i)
#pragma unroll
    for (int j = 0; j < 4; ++j)
      acc[i][j] = (f32x4){0.f, 0.f, 0.f, 0.f};

  for (int k0 = 0; k0 < HID; k0 += 32) {
#pragma unroll
    for (int h = 0; h < 2; ++h) {
      const int kb = skb + h * 2;
      const int kk = k0 + kb * 8;
      const size_t ao = (size_t)(bm + sr) * HID + kk;
      const size_t bo = (size_t)(bn + sr) * HID + kk;
      const int lo = (kb * 128 + sr) * 8;
      g2l16(Ah + ao, &AsH[lo]);
      g2l16(Al + ao, &AsL[lo]);
      g2l16(Bh + bo, &BsH[lo]);
      g2l16(Bl + bo, &BsL[lo]);
    }
    __syncthreads();
    bf8 ah[4], al[4], bh[4], bl[4];
#pragma unroll
    for (int i = 0; i < 4; ++i) {
      const int lo = (q * 128 + wr * 64 + i * 16 + l16) * 8;
      ah[i] = *(const bf8*)&AsH[lo];
      al[i] = *(const bf8*)&AsL[lo];
    }
#pragma unroll
    for (int j = 0; j < 4; ++j) {
      const int lo = (q * 128 + wc * 64 + j * 16 + l16) * 8;
      bh[j] = *(const bf8*)&BsH[lo];
      bl[j] = *(const bf8*)&BsL[lo];
    }
#pragma unroll
    for (int i = 0; i < 4; ++i)
#pragma unroll
      for (int j = 0; j < 4; ++j) {
        acc[i][j] = __builtin_amdgcn_mfma_f32_16x16x32_bf16(ah[i], bh[j], acc[i][j], 0, 0, 0);
        acc[i][j] = __builtin_amdgcn_mfma_f32_16x16x32_bf16(ah[i], bl[j], acc[i][j], 0, 0, 0);
        acc[i][j] = __builtin_amdgcn_mfma_f32_16x16x32_bf16(al[i], bh[j], acc[i][j], 0, 0, 0);
      }
    __syncthreads();
  }

#pragma unroll
  for (int j = 0; j < 4; ++j) {
    const int col = bn + wc * 64 + j * 16 + l16;
#pragma unroll
    for (int i = 0; i < 4; ++i) {
      const int row0 = bm + wr * 64 + i * 16 + q * 4;
#pragma unroll
      for (int r = 0; r < 4; ++r)
        C[(size_t)(row0 + r) * TT + col] = acc[i][j][r];
    }
  }
}

extern "C" void kernel_launch(void* const* d_in, const int* in_sizes, int n_in,
                              void* d_out, int out_size, void* d_ws, size_t ws_size,
                              hipStream_t stream)
{
  const int*   inputs     = (const int*)d_in[0];
  const int*   targets    = (const int*)d_in[1];
  const float* input_emb  = (const float*)d_in[2];
  const float* target_emb = (const float*)d_in[3];
  const float* conv_w     = (const float*)d_in[4];
  const float* conv_b     = (const float*)d_in[5];
  const float* dense_w    = (const float*)d_in[6];
  const float* dense_b    = (const float*)d_in[7];
  float* out = (float*)d_out;

  const long long SE = (long long)TT * HID;     // elems per batch (te/ie)
  const size_t SZ = (size_t)NB * SE * 2;        // 16,777,216 B bf16 region

  // workspace map (167,772,160 B total, proven capacity):
  // [0,SZ)        te_hi          -> ieT after logits
  // [SZ,..)       te_lo          -> attn padded (NB*PR+1 rows = 16,787,456 B)
  // [2SZ,3SZ)     ie_hi          -> convwb @ 2SZ+16K (25.2 MB, spans ie_lo)
  // [3SZ,4SZ)     ie_lo
  // [4SZ,4SZ+67M) logit fp32     -> hb bf16 after softmax
  // [4SZ+67M,end) Wbf bf16       -> densewb after attn GEMM
  char* base = (char*)d_ws;
  unsigned short* te_hi = (unsigned short*)(base);
  unsigned short* te_lo = (unsigned short*)(base + SZ);
  unsigned short* ie_hi = (unsigned short*)(base + 2 * SZ);
  unsigned short* ie_lo = (unsigned short*)(base + 3 * SZ);
  float*          logit = (float*)         (base + 4 * SZ);
  unsigned short* Wbf   = (unsigned short*)(base + 4 * SZ + (size_t)NB * TT * TT * 4);
  unsigned short* ieT     = (unsigned short*)(base);
  unsigned short* attnP   = (unsigned short*)(base + SZ);              // padded buffer base
  unsigned short* attnD   = attnP + (size_t)HID;                       // first data row
  unsigned short* convwb  = (unsigned short*)(base + 2 * SZ + 16384);
  unsigned short* hb      = (unsigned short*)(base + 4 * SZ);
  unsigned short* densewb = (unsigned short*)Wbf;

  // 1) gathers: te raw, ie scaled by sqrt(H)=32  (logits = te_raw . ie_scaled)
  gather_split_k<<<NB * TT, 256, 0, stream>>>(targets, target_emb, te_hi, te_lo, 1.0f);
  gather_split_k<<<NB * TT, 256, 0, stream>>>(inputs,  input_emb,  ie_hi, ie_lo, 32.0f);

  // 2) fused hi/lo logits
  gemm_logits_k<<<dim3(TT / 128, TT / 128, NB), 256, 0, stream>>>(
      te_hi, te_lo, ie_hi, ie_lo, logit);

  // 3) ieT[h][s] = ie_hi[s][h]  (overwrites te_hi, dead)
  transpose_bf_k<unsigned short><<<dim3(HID / 32, TT / 32, NB), 256, 0, stream>>>(
      ie_hi, ieT, TT, HID, SE, SE);

  // 4) softmax -> bf16 W
  softmax_bf_k<<<NB * TT, 256, 0, stream>>>(logit, Wbf);

  // 5) guard rows + attn[t][h] = W[t][s] . ieT[h][s] -> padded bf16 buffer
  zero_guard_k<<<NB + 1, 256, 0, stream>>>(attnP);
  gemm_bf16_k<1, 0, 0><<<dim3(HID / 128, TT / 128, NB), 256, 0, stream>>>(
      Wbf, (long long)TT * TT, TT, ieT, SE, TT,
      attnD, (long long)PR * HID, HID, TT, nullptr);

  // 6) weight transposes (convwb over dead ie region; densewb over dead Wbf)
  transpose_bf_k<float><<<dim3(UD / 32, (3 * HID) / 32, 1), 256, 0, stream>>>(
      conv_w, convwb, 3 * HID, UD, 0, 0);
  transpose_bf_k<float><<<dim3(HID / 32, UD / 32, 1), 256, 0, stream>>>(
      dense_w, densewb, UD, HID, 0, 0);

  // 7) conv: h = relu(b + im2col(attn).convwb^T) -> bf16 (over dead logit)
  gemm_bf16_k<1, 2, 1><<<dim3(UD / 128, TT / 128, NB), 256, 0, stream>>>(
      attnD, (long long)PR * HID, HID, convwb, 0, 3 * HID,
      hb, (long long)TT * UD, UD, 3 * HID, conv_b);

  // 8) dense: out = b + h.densewb^T  (fp32 out)
  gemm_bf16_k<0, 1, 0><<<dim3(HID / 128, TT / 128, NB), 256, 0, stream>>>(
      hb, (long long)TT * UD, UD, densewb, 0, UD,
      out, SE, HID, UD, dense_b);
}